// Round 7
// baseline (476.729 us; speedup 1.0000x reference)
//
#include <hip/hip_runtime.h>

#define B_  16
#define T_  2048
#define R_  256
#define NS_ 4

typedef unsigned short u16;
typedef __attribute__((ext_vector_type(8))) __bf16 bf16x8;
typedef __attribute__((ext_vector_type(4))) float f32x4;

__device__ __forceinline__ u16 f2bf(float f){
  union { float f; unsigned u; } x; x.f = f;
  unsigned r = x.u + 0x7FFFu + ((x.u >> 16) & 1u);
  return (u16)(r >> 16);
}
__device__ __forceinline__ float bf2f(u16 h){
  union { unsigned u; float f; } x; x.u = ((unsigned)h) << 16; return x.f;
}

// async global->LDS, 16B per lane. LDS dest must be wave-uniform base; HW
// writes lane i at base + i*16 (guide §5). Our chunk order matches that.
__device__ __forceinline__ void async_cp16(const void* g, void* l){
  __builtin_amdgcn_global_load_lds((__attribute__((address_space(1))) void*)g,
                                   (__attribute__((address_space(3))) void*)l,
                                   16, 0, 0);
}

// ---------------------------------------------------------------- convert
__global__ __launch_bounds__(256)
void cvt_kernel(const float* __restrict__ src, u16* __restrict__ dst, int n4){
  int i = blockIdx.x*256 + threadIdx.x;
  if (i >= n4) return;
  float4 f = ((const float4*)src)[i];
  ushort4 o;
  o.x = f2bf(f.x); o.y = f2bf(f.y); o.z = f2bf(f.z); o.w = f2bf(f.w);
  ((ushort4*)dst)[i] = o;
}

__global__ __launch_bounds__(256)
void zero_kernel(float* __restrict__ p, int n){
  int i = blockIdx.x*256 + threadIdx.x;
  if (i < n) p[i] = 0.0f;
}

// Zero the above-diagonal strips of P' that the 256-row pv A-tiles read but
// attn never writes: per (b,tT): rows [256tT, 256tT+128) x cols
// [256tT+128, 256tT+256). 4 MB total.
__global__ __launch_bounds__(256)
void pzero_kernel(u16* __restrict__ P){
  int blk = blockIdx.x;            // 0..127
  int b = blk & 15, tT = blk >> 4; // tT 0..7
  long long base = (long long)b*T_*T_ + (long long)(tT*256)*T_ + (tT*256 + 128);
  int r = threadIdx.x >> 1, h = threadIdx.x & 1;
  u16* p = P + base + (long long)r*T_ + h*64;
  uint4 z = {0u,0u,0u,0u};
  #pragma unroll
  for (int i=0;i<8;i++) ((uint4*)p)[i] = z;
}

// ------------------------------------------------- generic NT GEMM (bf16)
__global__ __launch_bounds__(256, 2)
void gemm_nt_bias(const u16* __restrict__ A, const u16* __restrict__ Bm,
                  u16* __restrict__ C, const float* __restrict__ bias,
                  int lda, int ldb, int ldc, int K,
                  long long sAn, long long sBb, long long sCz,
                  int sBiasN, int biasMode)
{
  __shared__ __align__(16) u16 As[128*32];
  __shared__ __align__(16) u16 Bs[128*32];
  int tid = threadIdx.x;
  int lane = tid & 63, wave = tid >> 6;
  int z = blockIdx.z;
  int nIdx = z & 3, bIdx = z >> 2;
  A    += (long long)nIdx * sAn;
  Bm   += (long long)bIdx * sBb;
  C    += (long long)z * sCz;
  bias += (long long)nIdx * sBiasN;
  int mBase = blockIdx.y * 128;
  int nBase = blockIdx.x * 128;
  int wm = (wave >> 1) * 64, wn = (wave & 1) * 64;
  int quad = lane >> 4, lc = lane & 15;

  f32x4 acc[4][4];
  #pragma unroll
  for (int i=0;i<4;i++)
    #pragma unroll
    for (int j=0;j<4;j++) acc[i][j] = (f32x4){0.f,0.f,0.f,0.f};

  for (int k0=0; k0<K; k0+=32){
    #pragma unroll
    for (int r=0;r<2;r++){
      int c = r*256 + tid;
      int row = c >> 2, col = (c & 3)*8;
      async_cp16(A  + (long long)(mBase+row)*lda + k0 + col, (void*)(As + (r*256 + wave*64)*8));
      async_cp16(Bm + (long long)(nBase+row)*ldb + k0 + col, (void*)(Bs + (r*256 + wave*64)*8));
    }
    __syncthreads();
    bf16x8 af[4], bfr[4];
    #pragma unroll
    for (int i=0;i<4;i++){
      af[i]  = *(const bf16x8*)(As + (wm + i*16 + lc)*32 + quad*8);
      bfr[i] = *(const bf16x8*)(Bs + (wn + i*16 + lc)*32 + quad*8);
    }
    #pragma unroll
    for (int i=0;i<4;i++)
      #pragma unroll
      for (int j=0;j<4;j++)
        acc[i][j] = __builtin_amdgcn_mfma_f32_16x16x32_bf16(af[i], bfr[j], acc[i][j], 0,0,0);
    __syncthreads();
  }
  // epilogue: C/D layout col=lane&15, row=quad*4+e (m89/m91 verified)
  #pragma unroll
  for (int i=0;i<4;i++){
    #pragma unroll
    for (int j=0;j<4;j++){
      int colG = nBase + wn + j*16 + lc;
      float bc = (biasMode==0) ? bias[colG] : 0.0f;
      #pragma unroll
      for (int e=0;e<4;e++){
        int rowG = mBase + wm + i*16 + quad*4 + e;
        float val = acc[i][j][e] + ((biasMode==0) ? bc : bias[rowG]);
        C[(long long)rowG*ldc + colG] = f2bf(val);
      }
    }
  }
}

// ------------------------------------- attention scores, single sweep
__global__ __launch_bounds__(256, 4)
void attn_kernel(const u16* __restrict__ qp, const u16* __restrict__ kp,
                 u16* __restrict__ P, float* __restrict__ lsum)
{
  __shared__ __align__(16) u16 Qs[64*32];
  __shared__ __align__(16) u16 Ks[128*32];
  int tid = threadIdx.x, lane = tid & 63, wave = tid >> 6;
  int b = blockIdx.y;
  int f = blockIdx.x;
  int t64 = 31;
  while (f >= (t64 >> 1) + 1){ f -= (t64 >> 1) + 1; t64--; }
  int sT = f;
  int tBase = t64 * 64;
  const u16* Q  = qp + ((long long)b*T_ + tBase) * R_;
  const u16* Kt = kp + (long long)b*T_*R_ + (long long)sT*128*R_;
  u16* Pb = P + (long long)b*T_*T_;
  const float scale = 0.0625f;     // 1/sqrt(256)
  int quad = lane >> 4, lc = lane & 15;
  int rowLoc = wave*16 + quad*4;

  f32x4 acc[8];
  #pragma unroll
  for (int j=0;j<8;j++) acc[j] = (f32x4){0.f,0.f,0.f,0.f};

  for (int k0=0;k0<R_;k0+=32){
    {
      int row = tid >> 2, col = (tid & 3)*8;
      async_cp16(Q + (long long)row*R_ + k0 + col, (void*)(Qs + (wave*64)*8));
    }
    #pragma unroll
    for (int r=0;r<2;r++){
      int c = r*256 + tid;
      int row = c >> 2, col = (c & 3)*8;
      async_cp16(Kt + (long long)row*R_ + k0 + col, (void*)(Ks + (r*256 + wave*64)*8));
    }
    __syncthreads();
    bf16x8 aq = *(const bf16x8*)(Qs + (wave*16 + lc)*32 + quad*8);
    #pragma unroll
    for (int j=0;j<8;j++){
      bf16x8 bk = *(const bf16x8*)(Ks + (j*16 + lc)*32 + quad*8);
      acc[j] = __builtin_amdgcn_mfma_f32_16x16x32_bf16(aq, bk, acc[j], 0,0,0);
    }
    __syncthreads();
  }

  int sCol0 = sT*128 + lc;
  #pragma unroll
  for (int e=0;e<4;e++){
    int t = tBase + rowLoc + e;
    long long ro = (long long)t * T_;
    float rs = 0.0f;
    #pragma unroll
    for (int j=0;j<8;j++){
      float v = acc[j][e]*scale;
      int s = sCol0 + j*16;
      if (s > t || v == 0.0f) v = -10000.0f;
      float p = __expf(v);            // exact 0 when masked
      rs += p;
      Pb[ro + s] = f2bf(p);
    }
    #pragma unroll
    for (int off=1; off<16; off<<=1)
      rs += __shfl_xor(rs, off, 64);
    if (lc == 0)
      atomicAdd(&lsum[b*T_ + t], rs);
  }
}

// --------------------------------------------------------------- PV GEMM
// out[b][n][t][r] = (1/l[t]) * sum_s P'[b][t][s] * VT[b][n*256+r][s]
// 256x256 tile, BK=64, 8 waves (2Mx4N), 512 threads, 8 phases per 2 K-tiles.
// R7 change: LDS GEOMETRY -> 128B rows (full BK=64 per row) + m201's exact
// st_16x32 swizzle (byte ^= ((byte>>9)&1)<<5, i.e. chunk ^= 2 if row&4).
// Why: with 64B rows only {word,chunk(2b),row&1} reach the bank field, so
// 8 lanes/bank-nibble is invariant under ANY chunk permutation -> the
// measured rigid 4.0 conflicts/read across R2/R4/R6. 128B rows give chunk
// 3 bank bits; the row-bit-2 XOR spreads rows across chunk slots.
// (m201 measured: conflicts 37.8M->267K, +29-35% on this exact geometry.)
// Staging: linear LDS dest (rule #21), inverse-swizzle on global source:
// lane L of a 64-row quarter writes row wave*8+(L>>3), LDS chunk L&7,
// from global chunk (L&7) ^ (((L>>5)&1)<<1). Reads: chunk = KH*4+quad,
// read at chunk ^ (2 if lc&4) (row&4 == lc&4 for all frag rows).
// Ledger (whole-K-tile granularity, re-derived): buf1 tile o=2j+1 staged
// p1(A,4 calls)+p2(B,4), vmcnt(0) POST-MFMA at p3 (queue holds exactly o's
// 8 calls), barrier, first read p4. buf0 next tile n0=2j+2 staged p5+p6,
// retired p7-post, read p8. WAW: buf1's prev occupant last read p7(prev),
// retired in p8's lgkm gates + barrier -> p1 stage safe; buf0 last read
// p3, retired p4 gates + barrier -> p5 stage safe. Prologue: tiles 0,1
// (16 calls), vmcnt(8) retires tile 0 exactly. lgkm gates unchanged
// (read pattern identical to R6): odd 7,6,5,4; even 11,10,9,8; final 3,2,1,0.
#define MF(A,Bx,C) __builtin_amdgcn_mfma_f32_16x16x32_bf16(A,Bx,C,0,0,0)
#define VM8 asm volatile("s_waitcnt vmcnt(8)" ::: "memory")
#define VM0 asm volatile("s_waitcnt vmcnt(0)" ::: "memory")
#define LGSB(N) do{ asm volatile("s_waitcnt lgkmcnt(" #N ")" ::: "memory"); \
                    __builtin_amdgcn_sched_barrier(0); }while(0)
#define NOP ((void)0)

// stage one full K-tile quarter-row-block per call; 4 calls = 256 rows x 64k
#define STAGE2_A(KT) do { \
  const u16* sp_ = aG + (int)((KT)*64); \
  u16* dp_ = (u16*)lds + (((KT)&1)*16384) + wave*512; \
  async_cp16(sp_ + stOff2,            dp_); \
  async_cp16(sp_ + stOff2 +  64*2048, dp_ + 4096); \
  async_cp16(sp_ + stOff2 + 128*2048, dp_ + 8192); \
  async_cp16(sp_ + stOff2 + 192*2048, dp_ + 12288); \
} while(0)
#define STAGE2_B(KT) do { \
  const u16* sp_ = bG + (int)((KT)*64); \
  u16* dp_ = (u16*)lds + (32768 + ((KT)&1)*16384) + wave*512; \
  async_cp16(sp_ + stOff2,            dp_); \
  async_cp16(sp_ + stOff2 +  64*2048, dp_ + 4096); \
  async_cp16(sp_ + stOff2 + 128*2048, dp_ + 8192); \
  async_cp16(sp_ + stOff2 + 192*2048, dp_ + 12288); \
} while(0)

// row stride 64 u16 (128B); chunk = KH*4+quad swizzled by row bit2 (=lc&4)
#define LDA_F(BUF,KH,CU,TI) (*(const bf16x8*)(&lds[(BUF)*16384 + (rbA + (CU)*64 + (TI)*16)*64 + (KH)*32 + qSw2]))
#define LDB_F(BUF,KH,JJ)    (*(const bf16x8*)(&lds[32768 + (BUF)*16384 + (rbB + (JJ)*16)*64 + (KH)*32 + qSw2]))

#define RD_A(D0,D1,D2,D3,BUF,KH,CU) do { \
  D0 = LDA_F(BUF,KH,CU,0); D1 = LDA_F(BUF,KH,CU,1); \
  D2 = LDA_F(BUF,KH,CU,2); D3 = LDA_F(BUF,KH,CU,3); } while(0)
#define RD_B(D0,D1,D2,D3,BUF,KH) do { \
  D0 = LDB_F(BUF,KH,0); D1 = LDB_F(BUF,KH,1); \
  D2 = LDB_F(BUF,KH,2); D3 = LDB_F(BUF,KH,3); } while(0)

#define MFG(CU,G,Ag,Q0,Q1,Q2,Q3) do { \
  acc[(CU)*4+(G)][0]=MF(Ag,Q0,acc[(CU)*4+(G)][0]); \
  acc[(CU)*4+(G)][1]=MF(Ag,Q1,acc[(CU)*4+(G)][1]); \
  acc[(CU)*4+(G)][2]=MF(Ag,Q2,acc[(CU)*4+(G)][2]); \
  acc[(CU)*4+(G)][3]=MF(Ag,Q3,acc[(CU)*4+(G)][3]); } while(0)

// Phase: PRE (reads/stages) -> counted-lgkm-gated MFMA groups -> POST (vm
// waits) -> barrier.
#define PH(CU,A0,A1,A2,A3,Q0,Q1,Q2,Q3,W3,W2,W1,W0,PRE,POST) do { \
  PRE; \
  LGSB(W3); \
  __builtin_amdgcn_s_setprio(1); \
  MFG(CU,0,A0,Q0,Q1,Q2,Q3); \
  LGSB(W2); \
  MFG(CU,1,A1,Q0,Q1,Q2,Q3); \
  LGSB(W1); \
  MFG(CU,2,A2,Q0,Q1,Q2,Q3); \
  LGSB(W0); \
  MFG(CU,3,A3,Q0,Q1,Q2,Q3); \
  __builtin_amdgcn_s_setprio(0); \
  POST; \
  asm volatile("" ::: "memory"); \
  __builtin_amdgcn_s_barrier(); \
} while(0)

__global__ __launch_bounds__(512, 2)
void pv_kernel(const u16* __restrict__ P, const u16* __restrict__ VT,
               const float* __restrict__ lsum, float* __restrict__ out)
{
  __shared__ __align__(16) u16 lds[65536];   // 128 KB: A 2x16384, B 2x16384
  int tid = threadIdx.x, lane = tid & 63, wave = tid >> 6;
  int f = blockIdx.x;
  int xcd = f & 7, s = f >> 3;
  int g = xcd + 8*(s >> 2);     // 0..127
  int jIdx = s & 3;             // 0..3 -> n index
  int b = g & 15;
  int tT = 7 - (g >> 4);        // 0..7, heavy first
  int t0abs = tT * 256;
  int nIt = 2*(tT + 1);         // iterations; tiles = 2*nIt

  const u16* aG = P  + (long long)b*T_*T_ + (long long)t0abs*T_;
  const u16* bG = VT + (long long)b*1024*T_ + (long long)(jIdx*256)*T_;

  // staging: lane L -> row wave*8+(L>>3), LDS chunk L&7, global chunk
  // (L&7)^swz, swz = ((L>>5)&1)<<1 (= row bit 2).
  int stOff2 = (wave*8 + (lane>>3))*2048 + (((lane&7) ^ (((lane>>5)&1)<<1))*8);

  // read-side per-lane constants
  int quad = lane >> 4, lc = lane & 15;
  int wm = wave >> 2, wn = wave & 3;             // 2M x 4N waves
  int qSw2 = (quad ^ ((lc >> 1) & 2)) * 8;       // chunk^2 if row&4 (row&4==lc&4)
  int rbA = wm*128 + lc;
  int rbB = wn*64 + lc;

  f32x4 acc[8][4];
  #pragma unroll
  for (int i=0;i<8;i++)
    #pragma unroll
    for (int j=0;j<4;j++) acc[i][j] = (f32x4){0.f,0.f,0.f,0.f};
  bf16x8 fA0,fA1,fA2,fA3, gA0,gA1,gA2,gA3;
  bf16x8 bX0,bX1,bX2,bX3, bY0,bY1,bY2,bY3;

  // prologue: tiles 0 and 1 fully staged (16 calls); vmcnt(8) retires
  // tile 0's 8 exactly -> pre-loop reads of tile 0 are cross-wave safe.
  STAGE2_A(0); STAGE2_B(0);
  STAGE2_A(1); STAGE2_B(1);
  VM8;
  __builtin_amdgcn_s_barrier();
  RD_B(bX0,bX1,bX2,bX3, 0,0);
  RD_A(fA0,fA1,fA2,fA3, 0,0,0);

  { // iteration 0: tile1 already staged by prologue (no p1/p2 stage)
    PH(0, fA0,fA1,fA2,fA3, bX0,bX1,bX2,bX3, 7,6,5,4,
       RD_A(gA0,gA1,gA2,gA3, 0,0,1), NOP);
    PH(1, gA0,gA1,gA2,gA3, bX0,bX1,bX2,bX3, 11,10,9,8,
       RD_B(bY0,bY1,bY2,bY3, 0,1); RD_A(fA0,fA1,fA2,fA3, 0,1,0), NOP);
    PH(0, fA0,fA1,fA2,fA3, bY0,bY1,bY2,bY3, 7,6,5,4,
       RD_A(gA0,gA1,gA2,gA3, 0,1,1), VM0);
    PH(1, gA0,gA1,gA2,gA3, bY0,bY1,bY2,bY3, 11,10,9,8,
       RD_B(bX0,bX1,bX2,bX3, 1,0); RD_A(fA0,fA1,fA2,fA3, 1,0,0), NOP);
    PH(0, fA0,fA1,fA2,fA3, bX0,bX1,bX2,bX3, 7,6,5,4,
       RD_A(gA0,gA1,gA2,gA3, 1,0,1); STAGE2_A(2), NOP);
    PH(1, gA0,gA1,gA2,gA3, bX0,bX1,bX2,bX3, 11,10,9,8,
       RD_B(bY0,bY1,bY2,bY3, 1,1); RD_A(fA0,fA1,fA2,fA3, 1,1,0); STAGE2_B(2), NOP);
    PH(0, fA0,fA1,fA2,fA3, bY0,bY1,bY2,bY3, 7,6,5,4,
       RD_A(gA0,gA1,gA2,gA3, 1,1,1), VM0);
    PH(1, gA0,gA1,gA2,gA3, bY0,bY1,bY2,bY3, 11,10,9,8,
       RD_B(bX0,bX1,bX2,bX3, 0,0); RD_A(fA0,fA1,fA2,fA3, 0,0,0), NOP);
  }
  for (int j = 1; j < nIt-1; ++j){
    int o = 2*j+1, n0 = 2*j+2;
    PH(0, fA0,fA1,fA2,fA3, bX0,bX1,bX2,bX3, 7,6,5,4,
       RD_A(gA0,gA1,gA2,gA3, 0,0,1); STAGE2_A(o), NOP);
    PH(1, gA0,gA1,gA2,gA3, bX0,bX1,bX2,bX3, 11,10,9,8,
       RD_B(bY0,bY1,bY2,bY3, 0,1); RD_A(fA0,fA1,fA2,fA3, 0,1,0); STAGE2_B(o), NOP);
    PH(0, fA0,fA1,fA2,fA3, bY0,bY1,bY2,bY3, 7,6,5,4,
       RD_A(gA0,gA1,gA2,gA3, 0,1,1), VM0);
    PH(1, gA0,gA1,gA2,gA3, bY0,bY1,bY2,bY3, 11,10,9,8,
       RD_B(bX0,bX1,bX2,bX3, 1,0); RD_A(fA0,fA1,fA2,fA3, 1,0,0), NOP);
    PH(0, fA0,fA1,fA2,fA3, bX0,bX1,bX2,bX3, 7,6,5,4,
       RD_A(gA0,gA1,gA2,gA3, 1,0,1); STAGE2_A(n0), NOP);
    PH(1, gA0,gA1,gA2,gA3, bX0,bX1,bX2,bX3, 11,10,9,8,
       RD_B(bY0,bY1,bY2,bY3, 1,1); RD_A(fA0,fA1,fA2,fA3, 1,1,0); STAGE2_B(n0), NOP);
    PH(0, fA0,fA1,fA2,fA3, bY0,bY1,bY2,bY3, 7,6,5,4,
       RD_A(gA0,gA1,gA2,gA3, 1,1,1), VM0);
    PH(1, gA0,gA1,gA2,gA3, bY0,bY1,bY2,bY3, 11,10,9,8,
       RD_B(bX0,bX1,bX2,bX3, 0,0); RD_A(fA0,fA1,fA2,fA3, 0,0,0), NOP);
  }
  { // final iteration: stage only kL (p1,p2); no n0 stage; no p8 reads.
    int kL = 2*nIt - 1;
    PH(0, fA0,fA1,fA2,fA3, bX0,bX1,bX2,bX3, 7,6,5,4,
       RD_A(gA0,gA1,gA2,gA3, 0,0,1); STAGE2_A(kL), NOP);
    PH(1, gA0,gA1,gA2,gA3, bX0,bX1,bX2,bX3, 11,10,9,8,
       RD_B(bY0,bY1,bY2,bY3, 0,1); RD_A(fA0,fA1,fA2,fA3, 0,1,0); STAGE2_B(kL), NOP);
    PH(0, fA0,fA1,fA2,fA3, bY0,bY1,bY2,bY3, 7,6,5,4,
       RD_A(gA0,gA1,gA2,gA3, 0,1,1), VM0);
    PH(1, gA0,gA1,gA2,gA3, bY0,bY1,bY2,bY3, 11,10,9,8,
       RD_B(bX0,bX1,bX2,bX3, 1,0); RD_A(fA0,fA1,fA2,fA3, 1,0,0), NOP);
    PH(0, fA0,fA1,fA2,fA3, bX0,bX1,bX2,bX3, 7,6,5,4,
       RD_A(gA0,gA1,gA2,gA3, 1,0,1), NOP);
    PH(1, gA0,gA1,gA2,gA3, bX0,bX1,bX2,bX3, 11,10,9,8,
       RD_B(bY0,bY1,bY2,bY3, 1,1); RD_A(fA0,fA1,fA2,fA3, 1,1,0), NOP);
    PH(0, fA0,fA1,fA2,fA3, bY0,bY1,bY2,bY3, 7,6,5,4,
       RD_A(gA0,gA1,gA2,gA3, 1,1,1), NOP);
    PH(1, gA0,gA1,gA2,gA3, bY0,bY1,bY2,bY3, 3,2,1,0, NOP, NOP);
  }

  // epilogue: C/D layout col=lane&15, row=quad*4+e (m89/m91 verified)
  const float* lrow = lsum + b*T_;
  #pragma unroll
  for (int i=0;i<8;i++){
    float rl[4];
    #pragma unroll
    for (int e=0;e<4;e++)
      rl[e] = __builtin_amdgcn_rcpf(lrow[t0abs + wm*128 + i*16 + quad*4 + e]);
    #pragma unroll
    for (int j2=0;j2<4;j2++){
      int rcol = wn*64 + j2*16 + lc;
      #pragma unroll
      for (int e=0;e<4;e++){
        int t = t0abs + wm*128 + i*16 + quad*4 + e;
        out[(((long long)b*NS_ + jIdx)*T_ + t)*R_ + rcol] = acc[i][j2][e] * rl[e];
      }
    }
  }
}

// ------------------------------------------------------------------ proj
__global__ __launch_bounds__(256)
void proj_kernel(const u16* __restrict__ VT, const float* __restrict__ wp,
                 const float* __restrict__ bp, float* __restrict__ proj){
  int gid = blockIdx.x*256 + threadIdx.x;   // 16*4*2048
  int bn = gid >> 11, t = gid & 2047;
  const u16* base = VT + (long long)bn*R_*T_ + t;
  float acc = bp[0];
  #pragma unroll 8
  for (int o=0;o<R_;o++)
    acc = fmaf(bf2f(base[(long long)o*T_]), wp[o], acc);
  proj[gid] = acc;
}

// ------------------------------------------------------- cov + loss
__global__ __launch_bounds__(256)
void loss_batch_kernel(const float* __restrict__ proj, float* __restrict__ partial){
  __shared__ float red[4][14];
  int tid = threadIdx.x, lane = tid & 63, wave = tid >> 6;
  int b = blockIdx.x;
  const float* pb = proj + b*NS_*T_;
  float s[14];
  #pragma unroll
  for (int kk=0;kk<14;kk++) s[kk]=0.0f;
  for (int t=tid; t<T_; t+=256){
    float x0 = pb[0*T_+t], x1 = pb[1*T_+t], x2 = pb[2*T_+t], x3 = pb[3*T_+t];
    s[0]+=x0; s[1]+=x1; s[2]+=x2; s[3]+=x3;
    s[4]+=x0*x0; s[5]+=x1*x0; s[6]+=x1*x1; s[7]+=x2*x0; s[8]+=x2*x1;
    s[9]+=x2*x2; s[10]+=x3*x0; s[11]+=x3*x1; s[12]+=x3*x2; s[13]+=x3*x3;
  }
  #pragma unroll
  for (int kk=0;kk<14;kk++){
    #pragma unroll
    for (int off=1; off<64; off<<=1)
      s[kk] += __shfl_xor(s[kk], off, 64);
  }
  if (lane == 0){
    #pragma unroll
    for (int kk=0;kk<14;kk++) red[wave][kk] = s[kk];
  }
  __syncthreads();
  if (tid == 0){
    float tot[14];
    #pragma unroll
    for (int kk=0;kk<14;kk++)
      tot[kk] = red[0][kk] + red[1][kk] + red[2][kk] + red[3][kk];
    const float invT  = 1.0f/(float)T_;
    const float invT1 = 1.0f/(float)(T_-1);
    float csum = 0.0f;
    #pragma unroll
    for (int n=0;n<4;n++){
      #pragma unroll
      for (int m=0;m<=n;m++){
        int id = n*(n+1)/2 + m;
        float c = (tot[4+id] - tot[n]*tot[m]*invT) * invT1;
        csum += (n==m) ? fabsf(c) : 2.0f*fabsf(c);
      }
    }
    partial[b] = 0.5f*csum;
  }
}

__global__ void loss_final_kernel(const float* __restrict__ partial,
                                  float* __restrict__ simOut){
  if (threadIdx.x == 0){
    float sim = 0.0f;
    #pragma unroll
    for (int b=0;b<B_;b++) sim += partial[b];
    simOut[0] = sim * (1.0f/(float)B_);
  }
}

// ----------------------------------------------------------------- launch
extern "C" void kernel_launch(void* const* d_in, const int* in_sizes, int n_in,
                              void* d_out, int out_size, void* d_ws, size_t ws_size,
                              hipStream_t stream)
{
  const float* q  = (const float*)d_in[0];
  const float* k  = (const float*)d_in[1];
  const float* v  = (const float*)d_in[2];
  const float* wq = (const float*)d_in[3];
  const float* bq = (const float*)d_in[4];
  const float* wk = (const float*)d_in[5];
  const float* bk = (const float*)d_in[6];
  const float* wv = (const float*)d_in[7];
  const float* bv = (const float*)d_in[8];
  const float* wp = (const float*)d_in[9];
  const float* bp = (const float*)d_in[10];
  float* out = (float*)d_out;

  // workspace layout (bytes); total ~286.6 MB
  char* ws = (char*)d_ws;
  u16* qbf   = (u16*)(ws + 0);          // 16 MB  (dead after qp GEMM)
  u16* kbf   = (u16*)(ws + 16777216);   // 16 MB  (dead after kp GEMM)
  u16* vbf   = (u16*)(ws + 33554432);   // 16 MB
  u16* wqbf  = (u16*)(ws + 50331648);   // 128 KB
  u16* wkbf  = (u16*)(ws + 50462720);   // 128 KB
  u16* wvbf  = (u16*)(ws + 50593792);   // 512 KB
  u16* qpbf  = (u16*)(ws + 51118080);   // 16 MB  [B*T][R] bf16
  u16* kpbf  = (u16*)(ws + 67895296);   // 16 MB
  u16* vtbf  = (u16*)(ws + 84672512);   // 64 MB  [B][NS*R][T] bf16 (vs^T, +bias)
  u16* pbuf  = (u16*)(ws + 151781376);  // 128 MB [B][T][T] bf16 (p' = exp(v))
  float* prj = (float*)(ws + 285999104);// 512 KB [B][NS][T] f32
  float* lpart = (float*)(ws + 0);      // 64 B, reuses dead qbf region
  float* lsum  = (float*)(ws + 16777216); // 128 KB [B][T] f32, reuses dead kbf

  // 0) fp32 -> bf16 conversions
  cvt_kernel<<<8192,256,0,stream>>>(q,  qbf, 2097152);
  cvt_kernel<<<8192,256,0,stream>>>(k,  kbf, 2097152);
  cvt_kernel<<<8192,256,0,stream>>>(v,  vbf, 2097152);
  cvt_kernel<<<64,  256,0,stream>>>(wq, wqbf, 16384);
  cvt_kernel<<<64,  256,0,stream>>>(wk, wkbf, 16384);
  cvt_kernel<<<256, 256,0,stream>>>(wv, wvbf, 65536);

  // 1) projections: qp = q@wq^T+bq, kp = k@wk^T+bk  (M=32768,N=256,K=256)
  dim3 gq(2,256,1);
  gemm_nt_bias<<<gq,256,0,stream>>>(qbf, wqbf, qpbf, bq, 256,256,256,256, 0,0,0, 0, 0);
  gemm_nt_bias<<<gq,256,0,stream>>>(kbf, wkbf, kpbf, bk, 256,256,256,256, 0,0,0, 0, 0);
  // vs^T: per (b,n): C[o][t] = wv[n] @ v[b]^T + bv[n]  (M=256,N=2048,K=256)
  dim3 gv(16,2,64);
  gemm_nt_bias<<<gv,256,0,stream>>>(wvbf, vbf, vtbf, bv, 256,256,2048,256,
                                    65536LL, 524288LL, 524288LL, 256, 1);

  // 2) zero l table + the P' strips pv's 256-row tiles read but attn
  //    never writes; then single-sweep attention
  zero_kernel<<<128,256,0,stream>>>(lsum, 32768);
  pzero_kernel<<<128,256,0,stream>>>(pbuf);
  dim3 ga(272,16,1);
  attn_kernel<<<ga,256,0,stream>>>(qpbf, kpbf, pbuf, lsum);

  // 3) out = (P' @ Vcat) / l   (256^2, 128B-row LDS + st_16x32 swizzle)
  pv_kernel<<<512,512,0,stream>>>(pbuf, vtbf, lsum, out);

  // 4) sim loss (proj -> per-batch cov partials -> final mean)
  proj_kernel<<<512,256,0,stream>>>(vtbf, wp, bp, prj);
  loss_batch_kernel<<<16,256,0,stream>>>(prj, lpart);
  loss_final_kernel<<<1,64,0,stream>>>(lpart, out + 33554432);
}